// Round 6
// baseline (339.519 us; speedup 1.0000x reference)
//
#include <hip/hip_runtime.h>
#include <cstdint>
#include <cstddef>

#define NB 64
#define NN 2048
#define ND 128
#define NK 1024
#define NTOT (NB * NN)          // 131072
#define P 8                     // slices per graph
#define EPG4 (NN * 32 / 4)      // 16384 int4 per graph
#define SLICE4 (EPG4 / P)       // 2048 int4 per slice
#define EB (NB * P)             // 512 edge-slice blocks
#define FULL4 (NTOT * 32)       // 4194304 float4 of out_full
#define DIST4 (2 * NB * NK * 32)
#define K1GRID 2048
#define K3GRID 1024             // 64 sort + 960 emit, 1024 threads each
#define K4GRID 2048

// ---- K1: hist (blocks 0..511, LDS slice-histogram -> global int atomics) || proj ----
__global__ __launch_bounds__(256) void k1_proj_hist(
    const float* __restrict__ feat, const float* __restrict__ W,
    const int4* __restrict__ src4, const int4* __restrict__ dst4,
    float* __restrict__ s, unsigned* __restrict__ outdeg, unsigned* __restrict__ indeg)
{
    __shared__ unsigned ho[NN];
    __shared__ unsigned hi2[NN];
    const int tid = threadIdx.x, gid = blockIdx.x;
    if (gid < EB) {
        for (int j = tid; j < NN; j += 256) { ho[j] = 0u; hi2[j] = 0u; }
        __syncthreads();
        const int4* sp = src4 + (size_t)gid * SLICE4;
        const int4* dp = dst4 + (size_t)gid * SLICE4;
        for (int i = tid; i < SLICE4; i += 256) {
            int4 a = sp[i]; int4 b = dp[i];
            atomicAdd(&ho[a.x & (NN-1)], 1u); atomicAdd(&ho[a.y & (NN-1)], 1u);
            atomicAdd(&ho[a.z & (NN-1)], 1u); atomicAdd(&ho[a.w & (NN-1)], 1u);
            atomicAdd(&hi2[b.x & (NN-1)], 1u); atomicAdd(&hi2[b.y & (NN-1)], 1u);
            atomicAdd(&hi2[b.z & (NN-1)], 1u); atomicAdd(&hi2[b.w & (NN-1)], 1u);
        }
        __syncthreads();
        const int g = gid >> 3;
        for (int j = tid; j < NN; j += 256) {
            atomicAdd(&outdeg[g * NN + j], ho[j]);    // int atomics: deterministic
            atomicAdd(&indeg[g * NN + j], hi2[j]);
        }
    } else {
        const float4* f4 = (const float4*)feat;
        const int l = tid & 31;
        const float4 w = ((const float4*)W)[l];
        for (int idx = (gid - EB) * 256 + tid; idx < FULL4; idx += (K1GRID - EB) * 256) {
            float4 v = f4[(size_t)idx];           // idx = node*32 + l
            float val = v.x*w.x + v.y*w.y + v.z*w.z + v.w*w.w;
            #pragma unroll
            for (int off = 16; off > 0; off >>= 1) val += __shfl_down(val, off);
            if (l == 0) s[idx >> 5] = val;
        }
    }
}

// ---- K2: per-slice scatter; last block per graph reduces -> score, t, gsum ----
__global__ __launch_bounds__(256) void k2_scatter(
    const int4* __restrict__ src4, const int4* __restrict__ dst4,
    const float* __restrict__ s, const unsigned* __restrict__ outdeg,
    const unsigned* __restrict__ indeg, const float* __restrict__ bptr,
    unsigned* __restrict__ done, float* __restrict__ part_a,
    float* __restrict__ score, float* __restrict__ t, float* __restrict__ gsum)
{
    __shared__ float ms[NN];
    __shared__ float acc[NN];
    __shared__ float wred[4];
    __shared__ unsigned lastFlag;
    const int gid = blockIdx.x, tid = threadIdx.x;
    const int g = gid >> 3;
    for (int j = tid; j < NN; j += 256) {
        ms[j] = s[g * NN + j] * rsqrtf(fmaxf((float)outdeg[g * NN + j], 1.0f));
        acc[j] = 0.0f;
    }
    __syncthreads();
    const int4* sp = src4 + (size_t)gid * SLICE4;
    const int4* dp = dst4 + (size_t)gid * SLICE4;
    for (int i = tid; i < SLICE4; i += 256) {
        int4 a = sp[i]; int4 b = dp[i];
        atomicAdd(&acc[b.x & (NN-1)], ms[a.x & (NN-1)]);
        atomicAdd(&acc[b.y & (NN-1)], ms[a.y & (NN-1)]);
        atomicAdd(&acc[b.z & (NN-1)], ms[a.z & (NN-1)]);
        atomicAdd(&acc[b.w & (NN-1)], ms[a.w & (NN-1)]);
    }
    __syncthreads();
    float* pa = part_a + (size_t)gid * NN;
    for (int j = tid; j < NN; j += 256) pa[j] = acc[j];

    // ---- last-block-per-graph tail: reduce 8 partials -> score/t/gsum (once) ----
    __threadfence();                                  // release part_a stores (device scope)
    if (tid == 0) lastFlag = (atomicAdd(&done[g], 1u) == P - 1) ? 1u : 0u;
    __syncthreads();
    if (!lastFlag) return;
    __threadfence();                                  // acquire other blocks' part_a
    const float bb = bptr[0];
    float e = 0.0f;
    for (int j = tid; j < NN; j += 256) {
        const float* pa2 = part_a + (size_t)g * P * NN + j;
        float a = 0.0f;
        #pragma unroll
        for (int p = 0; p < P; p++) a += pa2[(size_t)p * NN];   // fixed order: deterministic
        float sc = a * rsqrtf(fmaxf((float)indeg[g * NN + j], 1.0f)) + bb;
        score[g * NN + j] = sc;
        t[g * NN + j] = tanhf(sc);
        e += expf(sc);
    }
    #pragma unroll
    for (int off = 32; off > 0; off >>= 1) e += __shfl_down(e, off);
    if ((tid & 63) == 0) wred[tid >> 6] = e;
    __syncthreads();
    if (tid == 0) gsum[g] = wred[0] + wred[1] + wred[2] + wred[3];
}

// ---- K3 (1024 thr): sort blocks 0..63 (keys from precomputed score) ||
//      emit blocks 64..1023 (pure scale-copy: out_full = feat * t) ----
__global__ __launch_bounds__(1024) void k3_sortemit(
    const float* __restrict__ score, const float* __restrict__ t,
    const float* __restrict__ feat, float* __restrict__ out_full,
    float* __restrict__ perm)
{
    __shared__ unsigned long long key[NN];     // 16 KB
    __shared__ unsigned msk[64];
    __shared__ unsigned exz[64];
    const int gid = blockIdx.x, tid = threadIdx.x;
    if (gid < NB) {
        const int g = gid;
        for (int j = tid; j < NN; j += 1024) {
            float sc = score[g * NN + j];
            unsigned u  = __float_as_uint(sc);
            unsigned ok = (u & 0x80000000u) ? ~u : (u | 0x80000000u);  // order-preserving
            key[j] = ((unsigned long long)(~ok) << 32) | (unsigned)j;  // asc == desc score, asc idx
        }
        if (tid < 64) msk[tid] = 0u;
        __syncthreads();
        // bitonic sort 2048 keys ascending; 1 exchange per thread per pass
        for (unsigned k = 2; k <= NN; k <<= 1) {
            for (unsigned j = k >> 1; j > 0; j >>= 1) {
                for (unsigned t2 = tid; t2 < NN; t2 += 1024) {
                    unsigned ixj = t2 ^ j;
                    if (ixj > t2) {
                        bool up = ((t2 & k) == 0);
                        unsigned long long x = key[t2], y = key[ixj];
                        bool sw = up ? (x > y) : (x < y);
                        if (sw) { key[t2] = y; key[ixj] = x; }
                    }
                }
                __syncthreads();
            }
        }
        {   // top-K -> perm (tid covers NK exactly); membership bits
            unsigned local = (unsigned)(key[tid] & 0xFFFFFFFFu);
            perm[g * NK + tid] = (float)(g * NN + (int)local);
            atomicOr(&msk[local >> 5], 1u << (local & 31));
        }
        __syncthreads();
        if (tid < 64) {
            unsigned zc = 32u - (unsigned)__popc(msk[tid]);
            unsigned v = zc;
            #pragma unroll
            for (int off = 1; off < 64; off <<= 1) {
                unsigned o = __shfl_up(v, off);
                if (tid >= off) v += o;
            }
            exz[tid] = v - zc;                    // exclusive scan of zero counts
        }
        __syncthreads();
        float* permc = perm + NB * NK;
        for (int j = tid; j < NN; j += 1024) {
            unsigned w2 = msk[j >> 5];
            if (!((w2 >> (j & 31)) & 1u)) {
                unsigned pos = exz[j >> 5] + (unsigned)__popc(~w2 & ((1u << (j & 31)) - 1u));
                permc[g * NK + pos] = (float)(g * NN + j);
            }
        }
    } else {
        const float4* f4 = (const float4*)feat;
        float4* of4 = (float4*)out_full;
        for (size_t i = (size_t)(gid - NB) * 1024 + tid; i < (size_t)FULL4;
             i += (size_t)(K3GRID - NB) * 1024) {
            float tv = t[i >> 5];                 // broadcast across 32 threads/row
            float4 v = f4[i];
            of4[i] = make_float4(v.x * tv, v.y * tv, v.z * tv, v.w * tv);
        }
    }
}

// ---- K4: dist|com = row-permuted copy of (L3-hot) out_full; softmax tail ----
__global__ __launch_bounds__(256) void k4_distcom(
    const float4* __restrict__ full4, const float* __restrict__ perm_all,
    float4* __restrict__ od4, const float* __restrict__ score,
    const float* __restrict__ gsum, float* __restrict__ out_sm)
{
    const size_t gtid = (size_t)blockIdx.x * 256 + threadIdx.x;
    for (size_t i = gtid; i < (size_t)DIST4; i += (size_t)K4GRID * 256) {
        int orow = (int)(i >> 5), col = (int)(i & 31);
        int srow = (int)perm_all[orow];           // exact ints stored as float
        od4[i] = full4[(size_t)srow * 32 + col];  // rows already scaled by tanh
    }
    if (gtid < NTOT) {
        float tot = 0.0f;
        #pragma unroll
        for (int q = 0; q < NB; q++) tot += gsum[q];   // fixed order, uniform loads
        out_sm[gtid] = expf(score[gtid]) / tot;
    }
}

extern "C" void kernel_launch(void* const* d_in, const int* in_sizes, int n_in,
                              void* d_out, int out_size, void* d_ws, size_t ws_size,
                              hipStream_t stream) {
    const float* feat = (const float*)d_in[0];
    const float* W    = (const float*)d_in[1];
    const float* b    = (const float*)d_in[2];
    const int4*  src4 = (const int4*)d_in[3];
    const int4*  dst4 = (const int4*)d_in[4];
    float* out = (float*)d_out;

    // workspace layout (~7 MB)
    float*    s      = (float*)d_ws;                  // NTOT
    float*    score  = s + NTOT;                      // NTOT
    float*    t      = score + NTOT;                  // NTOT
    unsigned* outdeg = (unsigned*)(t + NTOT);         // NTOT
    unsigned* indeg  = outdeg + NTOT;                 // NTOT
    unsigned* done   = indeg + NTOT;                  // 64
    float*    part_a = (float*)(done + 64);           // EB*NN = 1M floats
    float*    gsum   = part_a + (size_t)EB * NN;      // 64

    // output layout (floats)
    float* out_dist = out;                            // dist | com contiguous
    float* out_full = out + 2 * (size_t)NB * NK * ND;
    float* out_perm = out_full + (size_t)NTOT * ND;   // perm | permc contiguous
    float* out_sm   = out_perm + 2 * (size_t)NB * NK;

    // zero outdeg, indeg, done in one memset (contiguous)
    hipMemsetAsync(outdeg, 0, (2 * (size_t)NTOT + 64) * sizeof(unsigned), stream);

    k1_proj_hist<<<K1GRID, 256, 0, stream>>>(feat, W, src4, dst4, s, outdeg, indeg);
    k2_scatter<<<EB, 256, 0, stream>>>(src4, dst4, s, outdeg, indeg, b, done,
                                       part_a, score, t, gsum);
    k3_sortemit<<<K3GRID, 1024, 0, stream>>>(score, t, feat, out_full, out_perm);
    k4_distcom<<<K4GRID, 256, 0, stream>>>((const float4*)out_full, out_perm,
                                           (float4*)out_dist, score, gsum, out_sm);
}

// Round 7
// 273.923 us; speedup vs baseline: 1.2395x; 1.2395x over previous
//
#include <hip/hip_runtime.h>
#include <cstdint>
#include <cstddef>

#define NB 64
#define NN 2048
#define ND 128
#define NK 1024
#define NTOT (NB * NN)          // 131072
#define P 8                     // slices per graph
#define EPG4 (NN * 32 / 4)      // 16384 int4 per graph
#define SLICE4 (EPG4 / P)       // 2048 int4 per slice
#define EB (NB * P)             // 512 edge-slice blocks
#define FULL4 (NTOT * 32)       // 4194304 float4 of out_full
#define DIST4 (2 * NB * NK * 32)
#define K1HIST 512
#define K1PROJ 1024
#define K1GRID (K1HIST + K1PROJ)
#define K3GRID 1024             // 64 sort + 960 emit, 1024 threads each
#define K4GRID 2048

// ---- K1 (1024 thr): src-only hist (blocks 0..511) || proj (blocks 512..1535) ----
__global__ __launch_bounds__(1024) void k1_proj_hist(
    const float* __restrict__ feat, const float* __restrict__ W,
    const int4* __restrict__ src4, float* __restrict__ s,
    unsigned* __restrict__ outdeg)
{
    __shared__ unsigned ho[NN];
    const int tid = threadIdx.x, gid = blockIdx.x;
    if (gid < K1HIST) {
        for (int j = tid; j < NN; j += 1024) ho[j] = 0u;
        __syncthreads();
        const int4* sp = src4 + (size_t)gid * SLICE4;
        for (int i = tid; i < SLICE4; i += 1024) {   // 2 iterations
            int4 a = sp[i];
            atomicAdd(&ho[a.x & (NN-1)], 1u); atomicAdd(&ho[a.y & (NN-1)], 1u);
            atomicAdd(&ho[a.z & (NN-1)], 1u); atomicAdd(&ho[a.w & (NN-1)], 1u);
        }
        __syncthreads();
        const int g = gid >> 3;
        for (int j = tid; j < NN; j += 1024)
            atomicAdd(&outdeg[g * NN + j], ho[j]);   // int atomics: deterministic
    } else {
        const float4* f4 = (const float4*)feat;
        const int l = tid & 31;
        const float4 w = ((const float4*)W)[l];
        for (int idx = (gid - K1HIST) * 1024 + tid; idx < FULL4; idx += K1PROJ * 1024) {
            float4 v = f4[(size_t)idx];              // idx = node*32 + l
            float val = v.x*w.x + v.y*w.y + v.z*w.z + v.w*w.w;
            #pragma unroll
            for (int off = 16; off > 0; off >>= 1) val += __shfl_down(val, off);
            if (l == 0) s[idx >> 5] = val;
        }
    }
}

// ---- K2 (1024 thr): per-slice scatter + indeg hist (dst4 read once) ----
__global__ __launch_bounds__(1024) void k2_scatter(
    const int4* __restrict__ src4, const int4* __restrict__ dst4,
    const float* __restrict__ s, const unsigned* __restrict__ outdeg,
    unsigned* __restrict__ indeg, float* __restrict__ part_a)
{
    __shared__ float ms[NN];
    __shared__ float acc[NN];
    __shared__ unsigned hi2[NN];
    const int gid = blockIdx.x, tid = threadIdx.x;
    const int g = gid >> 3;
    for (int j = tid; j < NN; j += 1024) {
        ms[j] = s[g * NN + j] * rsqrtf(fmaxf((float)outdeg[g * NN + j], 1.0f));
        acc[j] = 0.0f;
        hi2[j] = 0u;
    }
    __syncthreads();
    const int4* sp = src4 + (size_t)gid * SLICE4;
    const int4* dp = dst4 + (size_t)gid * SLICE4;
    for (int i = tid; i < SLICE4; i += 1024) {       // 2 iterations
        int4 a = sp[i]; int4 b = dp[i];
        atomicAdd(&acc[b.x & (NN-1)], ms[a.x & (NN-1)]);
        atomicAdd(&acc[b.y & (NN-1)], ms[a.y & (NN-1)]);
        atomicAdd(&acc[b.z & (NN-1)], ms[a.z & (NN-1)]);
        atomicAdd(&acc[b.w & (NN-1)], ms[a.w & (NN-1)]);
        atomicAdd(&hi2[b.x & (NN-1)], 1u); atomicAdd(&hi2[b.y & (NN-1)], 1u);
        atomicAdd(&hi2[b.z & (NN-1)], 1u); atomicAdd(&hi2[b.w & (NN-1)], 1u);
    }
    __syncthreads();
    float* pa = part_a + (size_t)gid * NN;
    for (int j = tid; j < NN; j += 1024) {
        pa[j] = acc[j];
        atomicAdd(&indeg[g * NN + j], hi2[j]);       // int atomics: deterministic
    }
}

// ---- K3 (1024 thr): sort blocks 0..63 || emit blocks 64..1023 (round-5 proven) ----
__global__ __launch_bounds__(1024) void k3_sortemit(
    const float* __restrict__ part_a, const unsigned* __restrict__ indeg,
    const float* __restrict__ bptr, const float* __restrict__ feat,
    float* __restrict__ out_full, float* __restrict__ score,
    float* __restrict__ perm, float* __restrict__ gsum)
{
    __shared__ unsigned long long key[NN];     // 16 KB
    __shared__ unsigned msk[64];
    __shared__ unsigned exz[64];
    __shared__ float wred[16];
    const int gid = blockIdx.x, tid = threadIdx.x;
    const float bb = bptr[0];
    if (gid < NB) {
        const int g = gid;
        float e = 0.0f;
        for (int j = tid; j < NN; j += 1024) {
            const float* pa = part_a + (size_t)g * P * NN + j;
            float a = 0.0f;
            #pragma unroll
            for (int p = 0; p < P; p++) a += pa[(size_t)p * NN];   // fixed order
            float sc = a * rsqrtf(fmaxf((float)indeg[g * NN + j], 1.0f)) + bb;
            score[g * NN + j] = sc;
            e += expf(sc);
            unsigned u  = __float_as_uint(sc);
            unsigned ok = (u & 0x80000000u) ? ~u : (u | 0x80000000u);  // order-preserving
            key[j] = ((unsigned long long)(~ok) << 32) | (unsigned)j;  // asc == desc score, asc idx
        }
        #pragma unroll
        for (int off = 32; off > 0; off >>= 1) e += __shfl_down(e, off);
        if ((tid & 63) == 0) wred[tid >> 6] = e;
        if (tid < 64) msk[tid] = 0u;
        __syncthreads();
        if (tid == 0) {
            float tot = 0.0f;
            #pragma unroll
            for (int q = 0; q < 16; q++) tot += wred[q];
            gsum[g] = tot;
        }
        // bitonic sort 2048 keys ascending; 1 exchange per thread per pass
        for (unsigned k = 2; k <= NN; k <<= 1) {
            for (unsigned j = k >> 1; j > 0; j >>= 1) {
                for (unsigned t2 = tid; t2 < NN; t2 += 1024) {
                    unsigned ixj = t2 ^ j;
                    if (ixj > t2) {
                        bool up = ((t2 & k) == 0);
                        unsigned long long x = key[t2], y = key[ixj];
                        bool sw = up ? (x > y) : (x < y);
                        if (sw) { key[t2] = y; key[ixj] = x; }
                    }
                }
                __syncthreads();
            }
        }
        {   // top-K -> perm (tid covers NK exactly); membership bits
            unsigned local = (unsigned)(key[tid] & 0xFFFFFFFFu);
            perm[g * NK + tid] = (float)(g * NN + (int)local);
            atomicOr(&msk[local >> 5], 1u << (local & 31));
        }
        __syncthreads();
        if (tid < 64) {
            unsigned zc = 32u - (unsigned)__popc(msk[tid]);
            unsigned v = zc;
            #pragma unroll
            for (int off = 1; off < 64; off <<= 1) {
                unsigned o = __shfl_up(v, off);
                if (tid >= off) v += o;
            }
            exz[tid] = v - zc;                    // exclusive scan of zero counts
        }
        __syncthreads();
        float* permc = perm + NB * NK;
        for (int j = tid; j < NN; j += 1024) {
            unsigned w2 = msk[j >> 5];
            if (!((w2 >> (j & 31)) & 1u)) {
                unsigned pos = exz[j >> 5] + (unsigned)__popc(~w2 & ((1u << (j & 31)) - 1u));
                permc[g * NK + pos] = (float)(g * NN + j);
            }
        }
    } else {
        const float4* f4 = (const float4*)feat;
        float4* of4 = (float4*)out_full;
        for (size_t i = (size_t)(gid - NB) * 1024 + tid; i < (size_t)FULL4;
             i += (size_t)(K3GRID - NB) * 1024) {
            int row = (int)(i >> 5);
            int g = row >> 11, local = row & (NN - 1);
            const float* pa = part_a + (size_t)g * P * NN + local;
            float a = 0.0f;
            #pragma unroll
            for (int p = 0; p < P; p++) a += pa[(size_t)p * NN];   // same order as sort
            float sc = a * rsqrtf(fmaxf((float)indeg[row], 1.0f)) + bb;
            float tv = tanhf(sc);
            float4 v = f4[i];
            of4[i] = make_float4(v.x * tv, v.y * tv, v.z * tv, v.w * tv);
        }
    }
}

// ---- K4: dist|com = row-permuted copy of (L3-hot) out_full; softmax tail ----
__global__ __launch_bounds__(256) void k4_distcom(
    const float4* __restrict__ full4, const float* __restrict__ perm_all,
    float4* __restrict__ od4, const float* __restrict__ score,
    const float* __restrict__ gsum, float* __restrict__ out_sm)
{
    const size_t gtid = (size_t)blockIdx.x * 256 + threadIdx.x;
    for (size_t i = gtid; i < (size_t)DIST4; i += (size_t)K4GRID * 256) {
        int orow = (int)(i >> 5), col = (int)(i & 31);
        int srow = (int)perm_all[orow];           // exact ints stored as float
        od4[i] = full4[(size_t)srow * 32 + col];  // rows already scaled by tanh
    }
    if (gtid < NTOT) {
        float tot = 0.0f;
        #pragma unroll
        for (int q = 0; q < NB; q++) tot += gsum[q];   // fixed order, uniform loads
        out_sm[gtid] = expf(score[gtid]) / tot;
    }
}

extern "C" void kernel_launch(void* const* d_in, const int* in_sizes, int n_in,
                              void* d_out, int out_size, void* d_ws, size_t ws_size,
                              hipStream_t stream) {
    const float* feat = (const float*)d_in[0];
    const float* W    = (const float*)d_in[1];
    const float* b    = (const float*)d_in[2];
    const int4*  src4 = (const int4*)d_in[3];
    const int4*  dst4 = (const int4*)d_in[4];
    float* out = (float*)d_out;

    // workspace layout (~7 MB)
    float*    s      = (float*)d_ws;                  // NTOT
    float*    score  = s + NTOT;                      // NTOT
    unsigned* outdeg = (unsigned*)(score + NTOT);     // NTOT
    unsigned* indeg  = outdeg + NTOT;                 // NTOT
    float*    part_a = (float*)(indeg + NTOT);        // EB*NN = 1M floats
    float*    gsum   = part_a + (size_t)EB * NN;      // 64

    // output layout (floats)
    float* out_dist = out;                            // dist | com contiguous
    float* out_full = out + 2 * (size_t)NB * NK * ND;
    float* out_perm = out_full + (size_t)NTOT * ND;   // perm | permc contiguous
    float* out_sm   = out_perm + 2 * (size_t)NB * NK;

    hipMemsetAsync(outdeg, 0, 2 * (size_t)NTOT * sizeof(unsigned), stream);

    k1_proj_hist<<<K1GRID, 1024, 0, stream>>>(feat, W, src4, s, outdeg);
    k2_scatter<<<EB, 1024, 0, stream>>>(src4, dst4, s, outdeg, indeg, part_a);
    k3_sortemit<<<K3GRID, 1024, 0, stream>>>(part_a, indeg, b, feat, out_full,
                                             score, out_perm, gsum);
    k4_distcom<<<K4GRID, 256, 0, stream>>>((const float4*)out_full, out_perm,
                                           (float4*)out_dist, score, gsum, out_sm);
}